// Round 4
// baseline (356.607 us; speedup 1.0000x reference)
//
#include <hip/hip_runtime.h>
#include <hip/hip_bf16.h>
#include <cstdint>

typedef __bf16 bf16_t;
typedef __bf16 bf16x8 __attribute__((ext_vector_type(8)));
typedef __bf16 bf16x4 __attribute__((ext_vector_type(4)));
typedef float f32x4 __attribute__((ext_vector_type(4)));

static constexpr int B = 16, N = 1024, D = 768;
static constexpr float SCALE = 0.03608439182435161f; // 768^-0.5

// async global->LDS, 16B per lane, wave-uniform LDS base + lane*16
#define ASYNC_COPY16(gptr, lptr)                                                          \
  __builtin_amdgcn_global_load_lds((const __attribute__((address_space(1))) void*)(gptr), \
                                   (__attribute__((address_space(3))) void*)(lptr), 16, 0, 0)

// ---------------- helpers ----------------
__device__ __forceinline__ float wave_red_max(float v) {
#pragma unroll
  for (int o = 32; o > 0; o >>= 1) v = fmaxf(v, __shfl_down(v, o, 64));
  return v;
}
__device__ __forceinline__ float wave_red_sum(float v) {
#pragma unroll
  for (int o = 32; o > 0; o >>= 1) v += __shfl_down(v, o, 64);
  return v;
}
__device__ __forceinline__ float block_max(float v, float* sm) {
  v = wave_red_max(v);
  int lane = threadIdx.x & 63, w = threadIdx.x >> 6;
  if (lane == 0) sm[w] = v;
  __syncthreads();
  return fmaxf(fmaxf(sm[0], sm[1]), fmaxf(sm[2], sm[3]));
}
__device__ __forceinline__ float block_sum(float v, float* sm) {
  v = wave_red_sum(v);
  int lane = threadIdx.x & 63, w = threadIdx.x >> 6;
  if (lane == 0) sm[w] = v;
  __syncthreads();
  return sm[0] + sm[1] + sm[2] + sm[3];
}

// ---------------- cast fp32 -> bf16 (4 elems / thread) ----------------
__global__ __launch_bounds__(256) void cast_f32_bf16_4(const float4* __restrict__ in,
                                                       bf16x4* __restrict__ out, int n4) {
  int i = blockIdx.x * 256 + threadIdx.x;
  if (i < n4) {
    float4 v = in[i];
    bf16x4 o;
    o.x = (bf16_t)v.x; o.y = (bf16_t)v.y; o.z = (bf16_t)v.z; o.w = (bf16_t)v.w;
    out[i] = o;
  }
}

// ---------------- transpose bf16 [B][N][D] -> [B][D][N] ----------------
__global__ __launch_bounds__(256) void transpose_bf16(const bf16_t* __restrict__ in,
                                                      bf16_t* __restrict__ out) {
  __shared__ bf16_t t[32][33];
  int b = blockIdx.z;
  int d0 = blockIdx.x * 32;
  int n0 = blockIdx.y * 32;
  int tx = threadIdx.x & 31;
  int ty = threadIdx.x >> 5; // 0..7
  const bf16_t* src = in + (size_t)b * N * D;
  bf16_t* dst = out + (size_t)b * N * D;
#pragma unroll
  for (int r = 0; r < 4; r++) {
    int n = n0 + ty + r * 8;
    t[ty + r * 8][tx] = src[(size_t)n * D + d0 + tx];
  }
  __syncthreads();
#pragma unroll
  for (int r = 0; r < 4; r++) {
    int d = d0 + ty + r * 8;
    dst[(size_t)d * N + n0 + tx] = t[tx][ty + r * 8];
  }
}

// ---------------- positional softmax: pos[p][n] ----------------
__global__ __launch_bounds__(256) void pos_softmax_k(const float* __restrict__ coords,
                                                     const float* __restrict__ pemb,
                                                     float* __restrict__ pos) {
  __shared__ float sm1[4], sm2[4];
  int p = blockIdx.x;
  int tid = threadIdx.x;
  float e[6];
#pragma unroll
  for (int k = 0; k < 6; k++) e[k] = pemb[p * 6 + k];
  float v[4];
#pragma unroll
  for (int i = 0; i < 4; i++) {
    int n = tid + i * 256;
    const float* c = coords + ((size_t)p * N + n) * 6;
    float s = 0.f;
#pragma unroll
    for (int k = 0; k < 6; k++) s += c[k] * e[k];
    v[i] = s;
  }
  float m = block_max(fmaxf(fmaxf(v[0], v[1]), fmaxf(v[2], v[3])), sm1);
  float ex[4], ls = 0.f;
#pragma unroll
  for (int i = 0; i < 4; i++) { ex[i] = __expf(v[i] - m); ls += ex[i]; }
  float sum = block_sum(ls, sm2);
  float inv = 1.f / sum;
#pragma unroll
  for (int i = 0; i < 4; i++) pos[(size_t)p * N + tid + i * 256] = ex[i] * inv;
}

// ---------------- softmax + gate + entropy; writes attn bf16 in place ----------------
__global__ __launch_bounds__(256) void attn_entropy_k(float* __restrict__ S,
                                                      const float* __restrict__ pos,
                                                      const float* __restrict__ gating,
                                                      const float* __restrict__ temp,
                                                      float* __restrict__ hmap) {
  __shared__ float sm1[4], sm2[4], sm3[4];
  size_t row = blockIdx.x; // 0 .. B*N-1
  int q = (int)(row & (size_t)(N - 1));
  int tid = threadIdx.x;
  float* Srow = S + row * N;
  float g = 1.f / (1.f + __expf(-gating[0]));
  float s[4];
#pragma unroll
  for (int i = 0; i < 4; i++) s[i] = Srow[tid + i * 256];
  float m = block_max(fmaxf(fmaxf(s[0], s[1]), fmaxf(s[2], s[3])), sm1);
  float e[4], ls = 0.f;
#pragma unroll
  for (int i = 0; i < 4; i++) { e[i] = __expf(s[i] - m); ls += e[i]; }
  float sum = block_sum(ls, sm2);
  float inv = 1.f / sum;
  const float* prow = pos + (size_t)q * N;
  float a[4], ent = 0.f;
#pragma unroll
  for (int i = 0; i < 4; i++) {
    float patch = e[i] * inv;
    float ps = prow[tid + i * 256];
    a[i] = (1.f - g) * patch + g * ps;
    ent += -a[i] * __logf(a[i] + 1e-8f);
  }
  float E = block_sum(ent, sm3);
  __syncthreads(); // all reads of Srow complete before bf16 overwrite
  bf16_t* arow = (bf16_t*)Srow; // in-place: bf16 row lives in first 2 KB of the 4 KB fp32 slot
#pragma unroll
  for (int i = 0; i < 4; i++) arow[tid + i * 256] = (bf16_t)a[i];
  // hmap = 2*(1 - sigmoid(z)) = 2/(1+exp(z)),  z = temp*E
  if (tid == 0) hmap[row] = 2.f / (1.f + __expf(temp[0] * E));
}

// ---------------- NT GEMM: 128x128 tile, BK=64, coalesced LDS-repack epilogue ------
// C[M][Nc] = A[M][K] * B[Nc][K]^T * scale
// 4 waves in 2x2, each wave 64x64 via 4x4 of 16x16x32 MFMA, 2 k-slices per iter
// (32 MFMA per barrier pair). Staging: global_load_lds 16B/lane, wave-uniform base.
// Epilogue: per-wave 32x68-f32 LDS region (reuses staging LDS after final barrier),
// repack acc -> full-cache-line coalesced stores (float4 / bf16x8).
template <typename OutT>
__global__ __launch_bounds__(256) void gemm_nt_128(const bf16_t* __restrict__ A, int lda, long long sA,
                                                   const bf16_t* __restrict__ Bm, int ldb, long long sB,
                                                   OutT* __restrict__ C, int ldc, long long sC,
                                                   int K, float scale) {
  // union: staging As[128][64] (16 KB) + Bs[128][64] (16 KB)  |  epilogue 4 x 32x68 f32 (34816 B)
  __shared__ __align__(16) char lds_raw[4 * 32 * 68 * 4];
  bf16_t* As = (bf16_t*)lds_raw;
  bf16_t* Bs = (bf16_t*)(lds_raw + 16384);

  const int tid = threadIdx.x;
  const int lane = tid & 63, wave = tid >> 6;
  const int wr = wave >> 1, wc = wave & 1; // 2x2 wave grid, each 64x64
  const int quad = lane >> 4, lr = lane & 15;
  const int tileN = blockIdx.x * 128, tileM = blockIdx.y * 128;
  A += (long long)blockIdx.z * sA + (long long)tileM * lda;
  Bm += (long long)blockIdx.z * sB + (long long)tileN * ldb;
  C += (long long)blockIdx.z * sC;

  // staging: wave w covers tile rows [w*32, w*32+32); issue i covers 8 rows.
  // lane l -> row += l/8, 16B chunk col (l%8)*8 elems. LDS order == lane order.
  const bf16_t* ag = A + (long long)(wave * 32 + (lane >> 3)) * lda + (lane & 7) * 8;
  const bf16_t* bg = Bm + (long long)(wave * 32 + (lane >> 3)) * ldb + (lane & 7) * 8;

  f32x4 acc[4][4];
#pragma unroll
  for (int i = 0; i < 4; i++)
#pragma unroll
    for (int j = 0; j < 4; j++) acc[i][j] = (f32x4){0.f, 0.f, 0.f, 0.f};

  for (int kt = 0; kt < K; kt += 64) {
#pragma unroll
    for (int i = 0; i < 4; i++) {
      ASYNC_COPY16(ag + (long long)i * 8 * lda + kt, &As[(wave * 32 + i * 8) * 64]);
      ASYNC_COPY16(bg + (long long)i * 8 * ldb + kt, &Bs[(wave * 32 + i * 8) * 64]);
    }
    __syncthreads();
#pragma unroll
    for (int kk = 0; kk < 2; kk++) {
      bf16x8 af[4], bfr[4];
#pragma unroll
      for (int i = 0; i < 4; i++) {
        af[i] = *(const bf16x8*)&As[(wr * 64 + i * 16 + lr) * 64 + kk * 32 + quad * 8];
        bfr[i] = *(const bf16x8*)&Bs[(wc * 64 + i * 16 + lr) * 64 + kk * 32 + quad * 8];
      }
#pragma unroll
      for (int mi = 0; mi < 4; mi++)
#pragma unroll
        for (int nj = 0; nj < 4; nj++)
          acc[mi][nj] = __builtin_amdgcn_mfma_f32_16x16x32_bf16(af[mi], bfr[nj], acc[mi][nj], 0, 0, 0);
    }
    __syncthreads();
  }

  // ---- epilogue: per-wave repack (region private to wave; loop's final barrier
  // guarantees all staging reads are done) ----
  float* epi = (float*)lds_raw + wave * (32 * 68);
#pragma unroll
  for (int c = 0; c < 2; c++) {
    // write phase: rows [c*32, c*32+32) of this wave's 64x64 quadrant
#pragma unroll
    for (int m2 = 0; m2 < 2; m2++) {
      int mi = c * 2 + m2;
#pragma unroll
      for (int nj = 0; nj < 4; nj++)
#pragma unroll
        for (int r = 0; r < 4; r++) {
          int lrow = m2 * 16 + quad * 4 + r; // 0..31
          epi[lrow * 68 + nj * 16 + lr] = acc[mi][nj][r] * scale;
        }
    }
    // read + coalesced store phase
    if constexpr (sizeof(OutT) == 4) {
#pragma unroll
      for (int seg = 0; seg < 8; seg++) {
        int lrow = seg * 4 + (lane >> 4);
        f32x4 v = *(const f32x4*)&epi[lrow * 68 + (lane & 15) * 4];
        long long grow = tileM + wr * 64 + c * 32 + lrow;
        int gcol = tileN + wc * 64 + (lane & 15) * 4;
        *(f32x4*)&C[grow * ldc + gcol] = v;
      }
    } else {
#pragma unroll
      for (int seg = 0; seg < 4; seg++) {
        int lrow = seg * 8 + (lane >> 3);
        const float* p = &epi[lrow * 68 + (lane & 7) * 8];
        f32x4 v0 = *(const f32x4*)&p[0];
        f32x4 v1 = *(const f32x4*)&p[4];
        bf16x8 o;
#pragma unroll
        for (int j = 0; j < 4; j++) { o[j] = (bf16_t)v0[j]; o[j + 4] = (bf16_t)v1[j]; }
        long long grow = tileM + wr * 64 + c * 32 + lrow;
        int gcol = tileN + wc * 64 + (lane & 7) * 8;
        *(bf16x8*)&C[grow * ldc + gcol] = o;
      }
    }
  }
}

extern "C" void kernel_launch(void* const* d_in, const int* in_sizes, int n_in,
                              void* d_out, int out_size, void* d_ws, size_t ws_size,
                              hipStream_t stream) {
  const float* x = (const float*)d_in[0];      // [B][N][D]
  const float* y = (const float*)d_in[1];      // [B][N][D]
  const float* coords = (const float*)d_in[2]; // [N][N][6]
  const float* W = (const float*)d_in[3];      // [D][D]
  const float* pemb = (const float*)d_in[4];   // [N][6]
  const float* gating = (const float*)d_in[5];
  const float* temp = (const float*)d_in[6];
  float* out = (float*)d_out;
  float* hmap = out + (size_t)B * N * D;

  char* ws = (char*)d_ws;
  bf16_t* xb = (bf16_t*)(ws + 0);          // 24 MB
  bf16_t* yb = (bf16_t*)(ws + 25165824);   // 24 MB
  bf16_t* yT = (bf16_t*)(ws + 50331648);   // 24 MB
  bf16_t* Wb = (bf16_t*)(ws + 75497472);   // 1.125 MB
  bf16_t* kb = (bf16_t*)(ws + 76677120);   // 24 MB
  float* pos = (float*)(ws + 101842944);   // 4 MB
  float* S   = (float*)(ws + 106037248);   // 64 MB  (attn bf16 written in place)

  const int BND = B * N * D; // 12582912

  cast_f32_bf16_4<<<BND / 4 / 256, 256, 0, stream>>>((const float4*)x, (bf16x4*)xb, BND / 4);
  cast_f32_bf16_4<<<BND / 4 / 256, 256, 0, stream>>>((const float4*)y, (bf16x4*)yb, BND / 4);
  cast_f32_bf16_4<<<(D * D / 4 + 255) / 256, 256, 0, stream>>>((const float4*)W, (bf16x4*)Wb, D * D / 4);
  transpose_bf16<<<dim3(D / 32, N / 32, B), 256, 0, stream>>>(yb, yT);
  pos_softmax_k<<<N, 256, 0, stream>>>(coords, pemb, pos);

  // K1: kb[16384][768] = yb * Wb^T
  gemm_nt_128<bf16_t><<<dim3(D / 128, (B * N) / 128, 1), 256, 0, stream>>>(
      yb, D, 0LL, Wb, D, 0LL, kb, D, 0LL, D, 1.0f);

  // K3: S[b][n][m] = SCALE * x[b] * k[b]^T
  gemm_nt_128<float><<<dim3(N / 128, N / 128, B), 256, 0, stream>>>(
      xb, D, (long long)N * D, kb, D, (long long)N * D, S, N, (long long)N * N, D, SCALE);

  // K4: softmax + gate + entropy; attn bf16 in place (row stride 2048 bf16)
  attn_entropy_k<<<B * N, 256, 0, stream>>>(S, pos, gating, temp, hmap);

  // K5: out[b][n][d] = attn[b] * y[b]  (B-operand = yT, NT form)
  gemm_nt_128<float><<<dim3(D / 128, N / 128, B), 256, 0, stream>>>(
      (const bf16_t*)S, 2 * N, (long long)N * 2 * N, yT, N, (long long)N * D, out, D, (long long)N * D, N, 1.0f);
}

// Round 5
// 325.299 us; speedup vs baseline: 1.0962x; 1.0962x over previous
//
#include <hip/hip_runtime.h>
#include <hip/hip_bf16.h>
#include <cstdint>

typedef __bf16 bf16_t;
typedef __bf16 bf16x8 __attribute__((ext_vector_type(8)));
typedef __bf16 bf16x4 __attribute__((ext_vector_type(4)));
typedef float f32x4 __attribute__((ext_vector_type(4)));

static constexpr int B = 16, N = 1024, D = 768;
static constexpr float SCALE = 0.03608439182435161f; // 768^-0.5

// async global->LDS, 16B per lane, wave-uniform LDS base + lane*16
#define ASYNC_COPY16(gptr, lptr)                                                          \
  __builtin_amdgcn_global_load_lds((const __attribute__((address_space(1))) void*)(gptr), \
                                   (__attribute__((address_space(3))) void*)(lptr), 16, 0, 0)

// ---------------- helpers ----------------
__device__ __forceinline__ float wave_red_max(float v) {
#pragma unroll
  for (int o = 32; o > 0; o >>= 1) v = fmaxf(v, __shfl_down(v, o, 64));
  return v;
}
__device__ __forceinline__ float wave_red_sum(float v) {
#pragma unroll
  for (int o = 32; o > 0; o >>= 1) v += __shfl_down(v, o, 64);
  return v;
}
__device__ __forceinline__ float block_max(float v, float* sm) {
  v = wave_red_max(v);
  int lane = threadIdx.x & 63, w = threadIdx.x >> 6;
  if (lane == 0) sm[w] = v;
  __syncthreads();
  return fmaxf(fmaxf(sm[0], sm[1]), fmaxf(sm[2], sm[3]));
}
__device__ __forceinline__ float block_sum(float v, float* sm) {
  v = wave_red_sum(v);
  int lane = threadIdx.x & 63, w = threadIdx.x >> 6;
  if (lane == 0) sm[w] = v;
  __syncthreads();
  return sm[0] + sm[1] + sm[2] + sm[3];
}

// ---------------- cast fp32 -> bf16 (4 elems / thread) ----------------
__global__ __launch_bounds__(256) void cast_f32_bf16_4(const float4* __restrict__ in,
                                                       bf16x4* __restrict__ out, int n4) {
  int i = blockIdx.x * 256 + threadIdx.x;
  if (i < n4) {
    float4 v = in[i];
    bf16x4 o;
    o.x = (bf16_t)v.x; o.y = (bf16_t)v.y; o.z = (bf16_t)v.z; o.w = (bf16_t)v.w;
    out[i] = o;
  }
}

// ---------------- transpose bf16 [B][N][D] -> [B][D][N] ----------------
__global__ __launch_bounds__(256) void transpose_bf16(const bf16_t* __restrict__ in,
                                                      bf16_t* __restrict__ out) {
  __shared__ bf16_t t[32][33];
  int b = blockIdx.z;
  int d0 = blockIdx.x * 32;
  int n0 = blockIdx.y * 32;
  int tx = threadIdx.x & 31;
  int ty = threadIdx.x >> 5; // 0..7
  const bf16_t* src = in + (size_t)b * N * D;
  bf16_t* dst = out + (size_t)b * N * D;
#pragma unroll
  for (int r = 0; r < 4; r++) {
    int n = n0 + ty + r * 8;
    t[ty + r * 8][tx] = src[(size_t)n * D + d0 + tx];
  }
  __syncthreads();
#pragma unroll
  for (int r = 0; r < 4; r++) {
    int d = d0 + ty + r * 8;
    dst[(size_t)d * N + n0 + tx] = t[tx][ty + r * 8];
  }
}

// ---------------- positional softmax: pos[p][n] ----------------
__global__ __launch_bounds__(256) void pos_softmax_k(const float* __restrict__ coords,
                                                     const float* __restrict__ pemb,
                                                     float* __restrict__ pos) {
  __shared__ float sm1[4], sm2[4];
  int p = blockIdx.x;
  int tid = threadIdx.x;
  float e[6];
#pragma unroll
  for (int k = 0; k < 6; k++) e[k] = pemb[p * 6 + k];
  float v[4];
#pragma unroll
  for (int i = 0; i < 4; i++) {
    int n = tid + i * 256;
    const float* c = coords + ((size_t)p * N + n) * 6;
    float s = 0.f;
#pragma unroll
    for (int k = 0; k < 6; k++) s += c[k] * e[k];
    v[i] = s;
  }
  float m = block_max(fmaxf(fmaxf(v[0], v[1]), fmaxf(v[2], v[3])), sm1);
  float ex[4], ls = 0.f;
#pragma unroll
  for (int i = 0; i < 4; i++) { ex[i] = __expf(v[i] - m); ls += ex[i]; }
  float sum = block_sum(ls, sm2);
  float inv = 1.f / sum;
#pragma unroll
  for (int i = 0; i < 4; i++) pos[(size_t)p * N + tid + i * 256] = ex[i] * inv;
}

// ---------------- softmax + gate + entropy; writes attn bf16 in place ----------------
__global__ __launch_bounds__(256) void attn_entropy_k(float* __restrict__ S,
                                                      const float* __restrict__ pos,
                                                      const float* __restrict__ gating,
                                                      const float* __restrict__ temp,
                                                      float* __restrict__ hmap) {
  __shared__ float sm1[4], sm2[4], sm3[4];
  size_t row = blockIdx.x; // 0 .. B*N-1
  int q = (int)(row & (size_t)(N - 1));
  int tid = threadIdx.x;
  float* Srow = S + row * N;
  float g = 1.f / (1.f + __expf(-gating[0]));
  float s[4];
#pragma unroll
  for (int i = 0; i < 4; i++) s[i] = Srow[tid + i * 256];
  float m = block_max(fmaxf(fmaxf(s[0], s[1]), fmaxf(s[2], s[3])), sm1);
  float e[4], ls = 0.f;
#pragma unroll
  for (int i = 0; i < 4; i++) { e[i] = __expf(s[i] - m); ls += e[i]; }
  float sum = block_sum(ls, sm2);
  float inv = 1.f / sum;
  const float* prow = pos + (size_t)q * N;
  float a[4], ent = 0.f;
#pragma unroll
  for (int i = 0; i < 4; i++) {
    float patch = e[i] * inv;
    float ps = prow[tid + i * 256];
    a[i] = (1.f - g) * patch + g * ps;
    ent += -a[i] * __logf(a[i] + 1e-8f);
  }
  float E = block_sum(ent, sm3);
  __syncthreads(); // all reads of Srow complete before bf16 overwrite
  bf16_t* arow = (bf16_t*)Srow; // in-place: bf16 row lives in first 2 KB of the 4 KB fp32 slot
#pragma unroll
  for (int i = 0; i < 4; i++) arow[tid + i * 256] = (bf16_t)a[i];
  // hmap = 2*(1 - sigmoid(z)) = 2/(1+exp(z)),  z = temp*E
  if (tid == 0) hmap[row] = 2.f / (1.f + __expf(temp[0] * E));
}

// ---------------- NT GEMM: 256x128 tile, BK=64, 8 waves, XCD-colocating swizzle ----
// C[M][Nc] = A[M][K] * B[Nc][K]^T * scale
// 8 waves in 4x2, each wave 64x64 via 4x4 of 16x16x32 MFMA (32 MFMA/barrier-pair).
// AI = 85 FLOP per staged byte (vs 64 at 128x128).
// swz!=0: remap blocks so XCD i (linear%8) owns batches [i*Gz/8, (i+1)*Gz/8) -> L2 reuse.
template <typename OutT>
__global__ __launch_bounds__(512) void gemm_nt_256(const bf16_t* __restrict__ A, int lda, long long sA,
                                                   const bf16_t* __restrict__ Bm, int ldb, long long sB,
                                                   OutT* __restrict__ C, int ldc, long long sC,
                                                   int K, float scale, int swz) {
  // union: staging As[256][64] (32 KB) + Bs[128][64] (16 KB) | epilogue 8 x 16x68 f32 (34816 B)
  __shared__ __align__(16) char lds_raw[49152];
  bf16_t* As = (bf16_t*)lds_raw;
  bf16_t* Bs = (bf16_t*)(lds_raw + 32768);

  const int tid = threadIdx.x;
  const int lane = tid & 63, wave = tid >> 6; // 8 waves
  const int wr = wave >> 1, wc = wave & 1;    // 4x2 wave grid, each 64x64
  const int quad = lane >> 4, lr = lane & 15;

  int bx = blockIdx.x, by = blockIdx.y, bz = blockIdx.z;
  if (swz) {
    int Gx = gridDim.x, Gy = gridDim.y, Gz = gridDim.z;
    int i = bx + Gx * (by + Gy * bz);
    int xcd = i & 7, slot = i >> 3;
    int T = Gx * Gy;
    int bpx = Gz >> 3; // batches per XCD (Gz=16 -> 2)
    bz = xcd * bpx + slot / T;
    int t = slot % T;
    bx = t % Gx;
    by = t / Gx;
  }
  const int tileN = bx * 128, tileM = by * 256;
  A += (long long)bz * sA + (long long)tileM * lda;
  Bm += (long long)bz * sB + (long long)tileN * ldb;
  C += (long long)bz * sC;

  // staging: wave w stages A rows [w*32, w*32+32) (4 issues x 8 rows) and
  // B rows [w*16, w*16+16) (2 issues x 8 rows). lane l -> row += l/8, col (l&7)*8.
  const bf16_t* ag = A + (long long)(wave * 32 + (lane >> 3)) * lda + (lane & 7) * 8;
  const bf16_t* bg = Bm + (long long)(wave * 16 + (lane >> 3)) * ldb + (lane & 7) * 8;

  f32x4 acc[4][4];
#pragma unroll
  for (int i = 0; i < 4; i++)
#pragma unroll
    for (int j = 0; j < 4; j++) acc[i][j] = (f32x4){0.f, 0.f, 0.f, 0.f};

  for (int kt = 0; kt < K; kt += 64) {
#pragma unroll
    for (int i = 0; i < 4; i++)
      ASYNC_COPY16(ag + (long long)i * 8 * lda + kt, &As[(wave * 32 + i * 8) * 64]);
#pragma unroll
    for (int i = 0; i < 2; i++)
      ASYNC_COPY16(bg + (long long)i * 8 * ldb + kt, &Bs[(wave * 16 + i * 8) * 64]);
    __syncthreads();
#pragma unroll
    for (int kk = 0; kk < 2; kk++) {
      bf16x8 af[4], bfr[4];
#pragma unroll
      for (int i = 0; i < 4; i++) {
        af[i] = *(const bf16x8*)&As[(wr * 64 + i * 16 + lr) * 64 + kk * 32 + quad * 8];
        bfr[i] = *(const bf16x8*)&Bs[(wc * 64 + i * 16 + lr) * 64 + kk * 32 + quad * 8];
      }
#pragma unroll
      for (int mi = 0; mi < 4; mi++)
#pragma unroll
        for (int nj = 0; nj < 4; nj++)
          acc[mi][nj] = __builtin_amdgcn_mfma_f32_16x16x32_bf16(af[mi], bfr[nj], acc[mi][nj], 0, 0, 0);
    }
    __syncthreads();
  }

  // ---- epilogue: per-wave repack, 16-row chunks (region private; final barrier above
  // guarantees staging reads done) ----
  float* epi = (float*)lds_raw + wave * (16 * 68);
#pragma unroll
  for (int mi = 0; mi < 4; mi++) {
    // write 16 rows x 64 cols of this wave's quadrant
#pragma unroll
    for (int nj = 0; nj < 4; nj++)
#pragma unroll
      for (int r = 0; r < 4; r++)
        epi[(quad * 4 + r) * 68 + nj * 16 + lr] = acc[mi][nj][r] * scale;
    // read + coalesced store
    if constexpr (sizeof(OutT) == 4) {
#pragma unroll
      for (int seg = 0; seg < 4; seg++) {
        int lrow = seg * 4 + (lane >> 4);
        f32x4 v = *(const f32x4*)&epi[lrow * 68 + (lane & 15) * 4];
        long long grow = tileM + wr * 64 + mi * 16 + lrow;
        int gcol = tileN + wc * 64 + (lane & 15) * 4;
        *(f32x4*)&C[grow * ldc + gcol] = v;
      }
    } else {
#pragma unroll
      for (int seg = 0; seg < 2; seg++) {
        int lrow = seg * 8 + (lane >> 3);
        const float* p = &epi[lrow * 68 + (lane & 7) * 8];
        f32x4 v0 = *(const f32x4*)&p[0];
        f32x4 v1 = *(const f32x4*)&p[4];
        bf16x8 o;
#pragma unroll
        for (int j = 0; j < 4; j++) { o[j] = (bf16_t)v0[j]; o[j + 4] = (bf16_t)v1[j]; }
        long long grow = tileM + wr * 64 + mi * 16 + lrow;
        int gcol = tileN + wc * 64 + (lane & 7) * 8;
        *(bf16x8*)&C[grow * ldc + gcol] = o;
      }
    }
  }
}

extern "C" void kernel_launch(void* const* d_in, const int* in_sizes, int n_in,
                              void* d_out, int out_size, void* d_ws, size_t ws_size,
                              hipStream_t stream) {
  const float* x = (const float*)d_in[0];      // [B][N][D]
  const float* y = (const float*)d_in[1];      // [B][N][D]
  const float* coords = (const float*)d_in[2]; // [N][N][6]
  const float* W = (const float*)d_in[3];      // [D][D]
  const float* pemb = (const float*)d_in[4];   // [N][6]
  const float* gating = (const float*)d_in[5];
  const float* temp = (const float*)d_in[6];
  float* out = (float*)d_out;
  float* hmap = out + (size_t)B * N * D;

  char* ws = (char*)d_ws;
  bf16_t* xb = (bf16_t*)(ws + 0);          // 24 MB
  bf16_t* yb = (bf16_t*)(ws + 25165824);   // 24 MB
  bf16_t* yT = (bf16_t*)(ws + 50331648);   // 24 MB
  bf16_t* Wb = (bf16_t*)(ws + 75497472);   // 1.125 MB
  bf16_t* kb = (bf16_t*)(ws + 76677120);   // 24 MB
  float* pos = (float*)(ws + 101842944);   // 4 MB
  float* S   = (float*)(ws + 106037248);   // 64 MB  (attn bf16 written in place)

  const int BND = B * N * D; // 12582912

  cast_f32_bf16_4<<<BND / 4 / 256, 256, 0, stream>>>((const float4*)x, (bf16x4*)xb, BND / 4);
  cast_f32_bf16_4<<<BND / 4 / 256, 256, 0, stream>>>((const float4*)y, (bf16x4*)yb, BND / 4);
  cast_f32_bf16_4<<<(D * D / 4 + 255) / 256, 256, 0, stream>>>((const float4*)W, (bf16x4*)Wb, D * D / 4);
  transpose_bf16<<<dim3(D / 32, N / 32, B), 256, 0, stream>>>(yb, yT);
  pos_softmax_k<<<N, 256, 0, stream>>>(coords, pemb, pos);

  // K1: kb[16384][768] = yb * Wb^T   (M=16384, N=768, K=768)
  gemm_nt_256<bf16_t><<<dim3(D / 128, (B * N) / 256, 1), 512, 0, stream>>>(
      yb, D, 0LL, Wb, D, 0LL, kb, D, 0LL, D, 1.0f, 0);

  // K3: S[b][n][m] = SCALE * x[b] * k[b]^T   (M=1024, N=1024, K=768)
  gemm_nt_256<float><<<dim3(N / 128, N / 256, B), 512, 0, stream>>>(
      xb, D, (long long)N * D, kb, D, (long long)N * D, S, N, (long long)N * N, D, SCALE, 1);

  // K4: softmax + gate + entropy; attn bf16 in place (row stride 2048 bf16)
  attn_entropy_k<<<B * N, 256, 0, stream>>>(S, pos, gating, temp, hmap);

  // K5: out[b][n][d] = attn[b] * y[b]   (M=1024, N=768, K=1024; B-operand = yT)
  gemm_nt_256<float><<<dim3(D / 128, N / 256, B), 512, 0, stream>>>(
      (const bf16_t*)S, 2 * N, (long long)N * 2 * N, yT, N, (long long)N * D, out, D, (long long)N * D, N, 1.0f, 1);
}